// Round 1
// baseline (414.800 us; speedup 1.0000x reference)
//
#include <hip/hip_runtime.h>
#include <cstddef>

#define EPSF 1e-12f
#define NW 900
#define NH 16
#define NC 128
#define NK 64
#define NNB 8
#define NCB 90      // 90 chunks of 10 yaw positions
#define CHW 10
#define NCOLS 160   // NH * CHW columns per chunk
#define NT 30       // windows
#define ODIM 256
#define DDIM 8192   // NK*NC

// ---------------------------------------------------------------------------
// K1: per (n, chunk): logits = conv_w @ x + b  -> softmax over k ->
//     P[k][c] = sum_col a[k][col] x[c][col],  PA[k] = sum_col a[k][col]
// ---------------------------------------------------------------------------
__global__ __launch_bounds__(256) void k1_assign(
    const float* __restrict__ x,       // [8][128][16][900]
    const float* __restrict__ conv_w,  // [64][128]
    const float* __restrict__ conv_b,  // [64]
    float* __restrict__ P,             // [8][90][64][128]
    float* __restrict__ PA)            // [8][90][64]
{
  __shared__ float lg[NK * 161];    // logits/a [64][161]; head reused as conv_w stage [64][33]
  __shared__ float xbuf[128 * 41];  // phase A view [32][161]=5152, phase B view [128][41]=5248

  const int bx = blockIdx.x;
  const int n = bx / NCB, cb = bx - n * NCB;
  const int t = threadIdx.x;
  const int k = t >> 2;   // 0..63
  const int cg = t & 3;   // 0..3

  const float* xn = x + (size_t)n * NC * NH * NW + cb * CHW;

  // ---- Phase A: logits ----
  float acc[40];
#pragma unroll
  for (int j = 0; j < 40; ++j) acc[j] = 0.f;

  for (int cc = 0; cc < 4; ++cc) {
    __syncthreads();
    for (int e = t; e < 32 * NCOLS; e += 256) {      // x chunk: 32 c x 160 col
      int c32 = e / NCOLS, col = e - c32 * NCOLS;
      int h = col / CHW, wi = col - h * CHW;
      xbuf[c32 * 161 + col] = xn[(size_t)(cc * 32 + c32) * (NH * NW) + h * NW + wi];
    }
    for (int e = t; e < NK * 32; e += 256) {         // conv_w chunk into lg area [64][33]
      int kk = e >> 5, c32 = e & 31;
      lg[kk * 33 + c32] = conv_w[kk * NC + cc * 32 + c32];
    }
    __syncthreads();
    for (int c32 = 0; c32 < 32; ++c32) {
      float wv = lg[k * 33 + c32];                   // broadcast x4, 16 banks: conflict-free
      const float* xr = &xbuf[c32 * 161 + cg * 40];
#pragma unroll
      for (int j = 0; j < 40; ++j) acc[j] += wv * xr[j];
    }
  }
  __syncthreads();  // done with conv_w staging area
  {
    float bk = conv_b[k];
#pragma unroll
    for (int j = 0; j < 40; ++j) lg[k * 161 + cg * 40 + j] = acc[j] + bk;
  }
  __syncthreads();

  // ---- softmax over k per column ----
  if (t < NCOLS) {
    float m = -1e30f;
    for (int kk = 0; kk < NK; ++kk) m = fmaxf(m, lg[kk * 161 + t]);
    float s = 0.f;
    for (int kk = 0; kk < NK; ++kk) { float e = __expf(lg[kk * 161 + t] - m); lg[kk * 161 + t] = e; s += e; }
    float inv = 1.f / s;
    for (int kk = 0; kk < NK; ++kk) lg[kk * 161 + t] *= inv;
  }
  __syncthreads();

  // ---- Phase B: P GEMM (thread owns c = cg + 4j to keep LDS banks distinct) ----
  float pacc[32];
#pragma unroll
  for (int j = 0; j < 32; ++j) pacc[j] = 0.f;
  float pa = 0.f;

  for (int cc = 0; cc < 4; ++cc) {   // column chunks of 40
    __syncthreads();
    for (int e = t; e < NC * 40; e += 256) {
      int c = e / 40, col = e - c * 40;
      int gcol = cc * 40 + col;
      int h = gcol / CHW, wi = gcol - h * CHW;
      xbuf[c * 41 + col] = xn[(size_t)c * (NH * NW) + h * NW + wi];
    }
    __syncthreads();
    for (int col = 0; col < 40; ++col) {
      float av = lg[k * 161 + cc * 40 + col];        // 16 addrs, 16 banks: free
      pa += av;
      const float* xr = &xbuf[cg * 41 + col];
#pragma unroll
      for (int j = 0; j < 32; ++j) pacc[j] += av * xr[j * 164];   // (cg+4j)*41+col
    }
  }

  float* Pp = P + ((size_t)(n * NCB + cb) * NK + k) * NC;
#pragma unroll
  for (int j = 0; j < 32; ++j) Pp[cg + 4 * j] = pacc[j];
  if (cg == 0) PA[(size_t)(n * NCB + cb) * NK + k] = pa;
}

// ---------------------------------------------------------------------------
// K2: window sums (20 chunks each), residual vs centers, intra + global norm
// ---------------------------------------------------------------------------
__global__ __launch_bounds__(256) void k2_vlad(
    const float* __restrict__ P, const float* __restrict__ PA,
    const float* __restrict__ centers, float* __restrict__ vlad)
{
  __shared__ float Ak[NK];
  __shared__ float red[4];
  const int b = blockIdx.x;
  const int n = b / NT, wt = b - n * NT;
  const int t = threadIdx.x;

  if (t < NK) {
    float s = 0.f;
    for (int i = 0; i < 20; ++i) {
      int cb = (3 * wt + 80 + i) % 90;
      s += PA[((size_t)n * NCB + cb) * NK + t];
    }
    Ak[t] = s;
  }
  __syncthreads();

  const int e0 = t * 32;      // thread owns 32 contiguous elements of the 8192 vector
  const int k = e0 >> 7;      // lanes 4m..4m+3 share k
  float v[32];
#pragma unroll
  for (int j = 0; j < 32; ++j) v[j] = 0.f;
  for (int i = 0; i < 20; ++i) {
    int cb = (3 * wt + 80 + i) % 90;
    const float* Pp = P + ((size_t)n * NCB + cb) * (NK * NC) + e0;
#pragma unroll
    for (int j = 0; j < 32; ++j) v[j] += Pp[j];
  }
  const float A = Ak[k];
  const float* ce = centers + e0;
  float ss = 0.f;
#pragma unroll
  for (int j = 0; j < 32; ++j) { float val = v[j] - ce[j] * A; v[j] = val; ss += val * val; }
  ss += __shfl_xor(ss, 1);
  ss += __shfl_xor(ss, 2);
  float rn = 1.f / fmaxf(sqrtf(ss), EPSF);
  float ts = 0.f;
#pragma unroll
  for (int j = 0; j < 32; ++j) { v[j] *= rn; ts += v[j] * v[j]; }
  ts += __shfl_xor(ts, 32);
  ts += __shfl_xor(ts, 16);
  ts += __shfl_xor(ts, 8);
  ts += __shfl_xor(ts, 4);
  ts += __shfl_xor(ts, 2);
  ts += __shfl_xor(ts, 1);
  if ((t & 63) == 0) red[t >> 6] = ts;
  __syncthreads();
  float total = red[0] + red[1] + red[2] + red[3];
  float g = 1.f / fmaxf(sqrtf(total), EPSF);
  float* vp = vlad + (size_t)b * DDIM + e0;
#pragma unroll
  for (int j = 0; j < 32; ++j) vp[j] = v[j] * g;
}

// ---------------------------------------------------------------------------
// K3: out_partial = vlad(240x8192) @ mlp_w^T, split-K x4, tiles 16r x 64o
// ---------------------------------------------------------------------------
__global__ __launch_bounds__(256) void k3_gemm(
    const float* __restrict__ vlad, const float* __restrict__ mlp_w,
    float* __restrict__ part)   // [4][240][256]
{
  __shared__ float va[16 * 65];
  __shared__ float wb[64 * 65];
  const int bx = blockIdx.x;
  const int rt = bx % 15;
  const int ot = (bx / 15) & 3;
  const int ks = bx / 60;
  const int t = threadIdx.x;
  const int r0 = (t >> 5) << 1;
  const int o0 = (t & 31) << 1;
  float a00 = 0.f, a01 = 0.f, a10 = 0.f, a11 = 0.f;
  const int d0 = ks * 2048;
  for (int dc = 0; dc < 2048; dc += 64) {
    __syncthreads();
    for (int e = t; e < 16 * 64; e += 256) {
      int r = e >> 6, dd = e & 63;
      va[r * 65 + dd] = vlad[(size_t)(rt * 16 + r) * DDIM + d0 + dc + dd];
    }
    for (int e = t; e < 64 * 64; e += 256) {
      int o = e >> 6, dd = e & 63;
      wb[o * 65 + dd] = mlp_w[(size_t)(ot * 64 + o) * DDIM + d0 + dc + dd];
    }
    __syncthreads();
#pragma unroll 8
    for (int dd = 0; dd < 64; ++dd) {
      float x0 = va[r0 * 65 + dd], x1 = va[(r0 + 1) * 65 + dd];
      float y0 = wb[o0 * 65 + dd], y1 = wb[(o0 + 1) * 65 + dd];
      a00 += x0 * y0; a01 += x0 * y1; a10 += x1 * y0; a11 += x1 * y1;
    }
  }
  float* pp = part + ((size_t)(ks * 240 + rt * 16)) * ODIM + ot * 64;
  pp[r0 * ODIM + o0]           = a00;
  pp[r0 * ODIM + o0 + 1]       = a01;
  pp[(r0 + 1) * ODIM + o0]     = a10;
  pp[(r0 + 1) * ODIM + o0 + 1] = a11;
}

// ---------------------------------------------------------------------------
// K4: sum split-K partials + bias, row-normalize 240 x 256
// ---------------------------------------------------------------------------
__global__ __launch_bounds__(256) void k4_out(
    const float* __restrict__ part, const float* __restrict__ bias,
    float* __restrict__ out)
{
  __shared__ float red[4];
  const int r = blockIdx.x;
  const int o = threadIdx.x;
  float v = bias[o];
#pragma unroll
  for (int s = 0; s < 4; ++s) v += part[((size_t)s * 240 + r) * ODIM + o];
  float ss = v * v;
  ss += __shfl_xor(ss, 32);
  ss += __shfl_xor(ss, 16);
  ss += __shfl_xor(ss, 8);
  ss += __shfl_xor(ss, 4);
  ss += __shfl_xor(ss, 2);
  ss += __shfl_xor(ss, 1);
  if ((o & 63) == 0) red[o >> 6] = ss;
  __syncthreads();
  float total = red[0] + red[1] + red[2] + red[3];
  out[(size_t)r * ODIM + o] = v / fmaxf(sqrtf(total), EPSF);
}

// ---------------------------------------------------------------------------
extern "C" void kernel_launch(void* const* d_in, const int* in_sizes, int n_in,
                              void* d_out, int out_size, void* d_ws, size_t ws_size,
                              hipStream_t stream) {
  const float* x       = (const float*)d_in[0];
  const float* centers = (const float*)d_in[1];
  const float* conv_w  = (const float*)d_in[2];
  const float* conv_b  = (const float*)d_in[3];
  const float* mlp_w   = (const float*)d_in[4];
  const float* mlp_b   = (const float*)d_in[5];
  float* out = (float*)d_out;

  float* ws   = (float*)d_ws;
  float* P    = ws;                          // 8*90*64*128 = 5,898,240 floats
  float* PA   = P + (size_t)5898240;         // 8*90*64     =    46,080
  float* vlad = PA + (size_t)46080;          // 240*8192    = 1,966,080
  float* part = vlad + (size_t)1966080;      // 4*240*256   =   245,760   (total 32.6 MB)

  k1_assign<<<dim3(NNB * NCB), dim3(256), 0, stream>>>(x, conv_w, conv_b, P, PA);
  k2_vlad  <<<dim3(NNB * NT),  dim3(256), 0, stream>>>(P, PA, centers, vlad);
  k3_gemm  <<<dim3(240),       dim3(256), 0, stream>>>(vlad, mlp_w, part);
  k4_out   <<<dim3(240),       dim3(256), 0, stream>>>(part, mlp_b, out);
}

// Round 3
// 283.448 us; speedup vs baseline: 1.4634x; 1.4634x over previous
//
#include <hip/hip_runtime.h>
#include <cstddef>

#define EPSF 1e-12f
#define NCB 90
#define NT 30
#define ODIM 256
#define DDIM 8192

// ---------------------------------------------------------------------------
// K1: per (n, chunk of 10 yaw = 160 cols): loop 5 sub-chunks of 32 cols:
//   stage x[128][32] -> logits (4 FMA/LDS-word) -> softmax over k ->
//   P[64][128] += a * x^T (4 FMA/LDS-word, register tile 4k x 8c)
// x is read from HBM exactly once. LDS 28.9 KB -> 4 blocks/CU.
// ---------------------------------------------------------------------------
__global__ __launch_bounds__(256, 4) void k1_assign(
    const float* __restrict__ x,       // [8][128][16][900]
    const float* __restrict__ conv_w,  // [64][128]
    const float* __restrict__ conv_b,  // [64]
    float* __restrict__ P,             // [8][90][64][128]
    float* __restrict__ PA)            // [8][90][64]
{
  __shared__ float xs[128 * 36];   // x sub-chunk [c][col], stride 36
  __shared__ float as_[64 * 36];   // logits -> exp(l-M), stride 36
  __shared__ float mx4[4 * 32];
  __shared__ float sm4[4 * 32];
  __shared__ float Mf[32];
  __shared__ float inv[32];

  const int bx = blockIdx.x;
  const int n = bx / NCB, cb = bx - n * NCB;
  const int t = threadIdx.x;
  const int kq = t >> 4;          // 0..15 -> k rows 4kq..4kq+3
  const int lo = t & 15;          // logits: 2 cols (2lo,2lo+1); P: c-set lo+16j
  const int colo = 2 * lo;

  const float* xn = x + (size_t)n * 128 * 14400 + cb * 10;

  float bk[4];
#pragma unroll
  for (int i = 0; i < 4; ++i) bk[i] = conv_b[4 * kq + i];

  float pacc[4][8];
#pragma unroll
  for (int i = 0; i < 4; ++i)
#pragma unroll
    for (int j = 0; j < 8; ++j) pacc[i][j] = 0.f;
  float pak = 0.f;  // PA accumulator (threads t<64, k=t)

  for (int cc = 0; cc < 5; ++cc) {
    __syncthreads();
    // ---- stage x[128][32] as float2 (pairs never cross a 10-run) ----
#pragma unroll
    for (int s = 0; s < 8; ++s) {
      int e2 = t + 256 * s;
      int c = e2 >> 4, p = e2 & 15;
      int g = cc * 32 + 2 * p;
      int h = g / 10, wi = g - 10 * h;
      float2 val = *(const float2*)(xn + (size_t)c * 14400 + h * 900 + wi);
      *(float2*)&xs[c * 36 + 2 * p] = val;
    }
    __syncthreads();

    // ---- logits: thread = 4 k-rows x 2 cols, full c sweep ----
    float l0[4] = {0.f, 0.f, 0.f, 0.f}, l1[4] = {0.f, 0.f, 0.f, 0.f};
#pragma unroll 4
    for (int c4 = 0; c4 < 128; c4 += 4) {
      float2 xv0 = *(const float2*)&xs[(c4 + 0) * 36 + colo];
      float2 xv1 = *(const float2*)&xs[(c4 + 1) * 36 + colo];
      float2 xv2 = *(const float2*)&xs[(c4 + 2) * 36 + colo];
      float2 xv3 = *(const float2*)&xs[(c4 + 3) * 36 + colo];
#pragma unroll
      for (int i = 0; i < 4; ++i) {
        float4 wv = *(const float4*)(conv_w + (size_t)(4 * kq + i) * 128 + c4);
        l0[i] += wv.x * xv0.x + wv.y * xv1.x + wv.z * xv2.x + wv.w * xv3.x;
        l1[i] += wv.x * xv0.y + wv.y * xv1.y + wv.z * xv2.y + wv.w * xv3.y;
      }
    }
#pragma unroll
    for (int i = 0; i < 4; ++i) {
      as_[(4 * kq + i) * 36 + colo]     = l0[i] + bk[i];
      as_[(4 * kq + i) * 36 + colo + 1] = l1[i] + bk[i];
    }
    __syncthreads();

    // ---- softmax over k (64) per column (32) ----
    if (t < 128) {
      int col = t & 31, kg = t >> 5;
      float m = -3.4e38f;
#pragma unroll
      for (int ii = 0; ii < 16; ++ii) m = fmaxf(m, as_[(kg * 16 + ii) * 36 + col]);
      mx4[kg * 32 + col] = m;
    }
    __syncthreads();
    if (t < 32) Mf[t] = fmaxf(fmaxf(mx4[t], mx4[32 + t]), fmaxf(mx4[64 + t], mx4[96 + t]));
    __syncthreads();
    if (t < 128) {
      int col = t & 31, kg = t >> 5;
      float M = Mf[col], s = 0.f;
#pragma unroll
      for (int ii = 0; ii < 16; ++ii) {
        int a = (kg * 16 + ii) * 36 + col;
        float e = __expf(as_[a] - M);
        as_[a] = e;
        s += e;
      }
      sm4[kg * 32 + col] = s;
    }
    __syncthreads();
    if (t < 32) inv[t] = 1.0f / (sm4[t] + sm4[32 + t] + sm4[64 + t] + sm4[96 + t]);
    __syncthreads();

    // ---- P accumulate: tile 4k x 8c per thread, dot over 32 cols ----
#pragma unroll 2
    for (int colb = 0; colb < 8; ++colb) {
      float4 iv = *(const float4*)&inv[colb * 4];
      float4 av[4];
#pragma unroll
      for (int i = 0; i < 4; ++i) {
        av[i] = *(const float4*)&as_[(4 * kq + i) * 36 + colb * 4];
        av[i].x *= iv.x; av[i].y *= iv.y; av[i].z *= iv.z; av[i].w *= iv.w;
      }
#pragma unroll
      for (int j = 0; j < 8; ++j) {
        float4 xv = *(const float4*)&xs[(lo + 16 * j) * 36 + colb * 4];
#pragma unroll
        for (int i = 0; i < 4; ++i) {
          pacc[i][j] += av[i].x * xv.x + av[i].y * xv.y + av[i].z * xv.z + av[i].w * xv.w;
        }
      }
    }
    // ---- PA: one wave accumulates sum of a per k ----
    if (t < 64) {
#pragma unroll
      for (int cb4 = 0; cb4 < 8; ++cb4) {
        float4 e4 = *(const float4*)&as_[t * 36 + cb4 * 4];
        float4 iv = *(const float4*)&inv[cb4 * 4];
        pak += e4.x * iv.x + e4.y * iv.y + e4.z * iv.z + e4.w * iv.w;
      }
    }
  }

  float* Pp = P + (size_t)(n * NCB + cb) * 64 * 128;
#pragma unroll
  for (int i = 0; i < 4; ++i)
#pragma unroll
    for (int j = 0; j < 8; ++j)
      Pp[(4 * kq + i) * 128 + lo + 16 * j] = pacc[i][j];
  if (t < 64) PA[(size_t)(n * NCB + cb) * 64 + t] = pak;
}

// ---------------------------------------------------------------------------
// K2: window sums (20 chunks), residual, intra-norm; per-eb global-ss -> gss.
// Grid: 240 windows x 4 element-blocks of 2048.
// ---------------------------------------------------------------------------
__global__ __launch_bounds__(256) void k2_vlad(
    const float* __restrict__ P, const float* __restrict__ PA,
    const float* __restrict__ centers, float* __restrict__ vlad,
    float* __restrict__ gss)
{
  __shared__ float Ak[16];
  __shared__ float red[4];
  const int b = blockIdx.x;
  const int win = b >> 2, eb = b & 3;
  const int n = win / NT, wt = win - n * NT;
  const int t = threadIdx.x;

  if (t < 64) {
    int kk = t >> 2, ii = t & 3;
    float s = 0.f;
#pragma unroll
    for (int ss = 0; ss < 5; ++ss) {
      int i = ii + 4 * ss;
      int cb = (3 * wt + 80 + i) % 90;
      s += PA[((size_t)n * NCB + cb) * 64 + eb * 16 + kk];
    }
    s += __shfl_xor(s, 1);
    s += __shfl_xor(s, 2);
    if (ii == 0) Ak[kk] = s;
  }
  __syncthreads();

  const int e0 = eb * 2048 + t * 8;
  float v[8];
#pragma unroll
  for (int j = 0; j < 8; ++j) v[j] = 0.f;
#pragma unroll 5
  for (int i = 0; i < 20; ++i) {
    int cb = (3 * wt + 80 + i) % 90;
    const float* Pp = P + ((size_t)n * NCB + cb) * DDIM + e0;
    float4 u0 = *(const float4*)Pp;
    float4 u1 = *(const float4*)(Pp + 4);
    v[0] += u0.x; v[1] += u0.y; v[2] += u0.z; v[3] += u0.w;
    v[4] += u1.x; v[5] += u1.y; v[6] += u1.z; v[7] += u1.w;
  }
  const float A = Ak[t >> 4];
  const float* ce = centers + e0;
  float ss8 = 0.f;
#pragma unroll
  for (int j = 0; j < 8; ++j) {
    float val = v[j] - ce[j] * A;
    v[j] = val;
    ss8 += val * val;
  }
  float ssg = ss8;
  ssg += __shfl_xor(ssg, 1);
  ssg += __shfl_xor(ssg, 2);
  ssg += __shfl_xor(ssg, 4);
  ssg += __shfl_xor(ssg, 8);
  float rn = 1.f / fmaxf(sqrtf(ssg), EPSF);
#pragma unroll
  for (int j = 0; j < 8; ++j) v[j] *= rn;
  // global-norm partial: full 64-lane butterfly (R2 bug: only xor16/32 -> 1/16 of sum)
  float ts = ss8 * rn * rn;
  ts += __shfl_xor(ts, 1);
  ts += __shfl_xor(ts, 2);
  ts += __shfl_xor(ts, 4);
  ts += __shfl_xor(ts, 8);
  ts += __shfl_xor(ts, 16);
  ts += __shfl_xor(ts, 32);
  if ((t & 63) == 0) red[t >> 6] = ts;
  __syncthreads();
  if (t == 0) gss[(size_t)win * 4 + eb] = red[0] + red[1] + red[2] + red[3];

  float* vp = vlad + (size_t)win * DDIM + e0;
  *(float4*)vp = make_float4(v[0], v[1], v[2], v[3]);
  *(float4*)(vp + 4) = make_float4(v[4], v[5], v[6], v[7]);
}

// ---------------------------------------------------------------------------
// K3: part = (g .* vlad)(240x8192) @ mlp_w^T, split-K x8, tile 16r x 128o,
// transposed weight tile in LDS (conflict-free), 2r x 4o per thread.
// ---------------------------------------------------------------------------
__global__ __launch_bounds__(256) void k3_gemm(
    const float* __restrict__ vlad, const float* __restrict__ gss,
    const float* __restrict__ mlp_w, float* __restrict__ part)  // [8][240][256]
{
  __shared__ float va[16 * 68];
  __shared__ float wbt[64 * 129];
  __shared__ float ga[16];
  const int bx = blockIdx.x;
  const int rt = bx % 15;
  const int hx = bx / 15;
  const int ot = hx & 1, ks = hx >> 1;
  const int t = threadIdx.x;

  if (t < 16) {
    int r = rt * 16 + t;
    float s = gss[r * 4] + gss[r * 4 + 1] + gss[r * 4 + 2] + gss[r * 4 + 3];
    ga[t] = 1.f / fmaxf(sqrtf(s), EPSF);
  }

  const int rr = (t >> 5) << 1;   // 0,2,..,14
  const int o0 = t & 31;
  float acc[2][4];
#pragma unroll
  for (int a = 0; a < 2; ++a)
#pragma unroll
    for (int u = 0; u < 4; ++u) acc[a][u] = 0.f;

  const int d0 = ks * 1024;
  for (int dc = 0; dc < 1024; dc += 64) {
    __syncthreads();
    {
      int r = t >> 4, dq = t & 15;
      float4 u = *(const float4*)(vlad + (size_t)(rt * 16 + r) * DDIM + d0 + dc + 4 * dq);
      float g = ga[r];
      u.x *= g; u.y *= g; u.z *= g; u.w *= g;
      *(float4*)&va[r * 68 + 4 * dq] = u;
    }
#pragma unroll
    for (int s = 0; s < 8; ++s) {
      int f = t + 256 * s;
      int o = f >> 4, dq = f & 15;
      float4 u = *(const float4*)(mlp_w + (size_t)(ot * 128 + o) * DDIM + d0 + dc + 4 * dq);
      wbt[(4 * dq + 0) * 129 + o] = u.x;
      wbt[(4 * dq + 1) * 129 + o] = u.y;
      wbt[(4 * dq + 2) * 129 + o] = u.z;
      wbt[(4 * dq + 3) * 129 + o] = u.w;
    }
    __syncthreads();
#pragma unroll 8
    for (int dd = 0; dd < 64; ++dd) {
      float x0 = va[rr * 68 + dd];
      float x1 = va[(rr + 1) * 68 + dd];
      float y0 = wbt[dd * 129 + o0];
      float y1 = wbt[dd * 129 + o0 + 32];
      float y2 = wbt[dd * 129 + o0 + 64];
      float y3 = wbt[dd * 129 + o0 + 96];
      acc[0][0] += x0 * y0; acc[0][1] += x0 * y1; acc[0][2] += x0 * y2; acc[0][3] += x0 * y3;
      acc[1][0] += x1 * y0; acc[1][1] += x1 * y1; acc[1][2] += x1 * y2; acc[1][3] += x1 * y3;
    }
  }
  float* pp = part + ((size_t)ks * 240 + rt * 16) * ODIM + ot * 128;
#pragma unroll
  for (int a = 0; a < 2; ++a)
#pragma unroll
    for (int u = 0; u < 4; ++u)
      pp[(rr + a) * ODIM + o0 + 32 * u] = acc[a][u];
}

// ---------------------------------------------------------------------------
// K4: sum split-K partials + bias, row-normalize 240 x 256
// ---------------------------------------------------------------------------
__global__ __launch_bounds__(256) void k4_out(
    const float* __restrict__ part, const float* __restrict__ bias,
    float* __restrict__ out)
{
  __shared__ float red[4];
  const int r = blockIdx.x;
  const int o = threadIdx.x;
  float v = bias[o];
#pragma unroll
  for (int s = 0; s < 8; ++s) v += part[((size_t)s * 240 + r) * ODIM + o];
  float ss = v * v;
  ss += __shfl_xor(ss, 32);
  ss += __shfl_xor(ss, 16);
  ss += __shfl_xor(ss, 8);
  ss += __shfl_xor(ss, 4);
  ss += __shfl_xor(ss, 2);
  ss += __shfl_xor(ss, 1);
  if ((o & 63) == 0) red[o >> 6] = ss;
  __syncthreads();
  float total = red[0] + red[1] + red[2] + red[3];
  out[(size_t)r * ODIM + o] = v / fmaxf(sqrtf(total), EPSF);
}

// ---------------------------------------------------------------------------
extern "C" void kernel_launch(void* const* d_in, const int* in_sizes, int n_in,
                              void* d_out, int out_size, void* d_ws, size_t ws_size,
                              hipStream_t stream) {
  const float* x       = (const float*)d_in[0];
  const float* centers = (const float*)d_in[1];
  const float* conv_w  = (const float*)d_in[2];
  const float* conv_b  = (const float*)d_in[3];
  const float* mlp_w   = (const float*)d_in[4];
  const float* mlp_b   = (const float*)d_in[5];
  float* out = (float*)d_out;

  float* ws   = (float*)d_ws;
  float* P    = ws;                       // 8*90*64*128 = 5,898,240 floats
  float* PA   = P + (size_t)5898240;      // 46,080
  float* vlad = PA + (size_t)46080;       // 240*8192 = 1,966,080
  float* gss  = vlad + (size_t)1966080;   // 960
  float* part = ws;                       // [8][240][256] overlays dead P (31.7 MB total)

  k1_assign<<<dim3(8 * NCB), dim3(256), 0, stream>>>(x, conv_w, conv_b, P, PA);
  k2_vlad  <<<dim3(8 * NT * 4), dim3(256), 0, stream>>>(P, PA, centers, vlad, gss);
  k3_gemm  <<<dim3(240), dim3(256), 0, stream>>>(vlad, gss, mlp_w, part);
  k4_out   <<<dim3(240), dim3(256), 0, stream>>>(part, mlp_b, out);
}

// Round 4
// 187.068 us; speedup vs baseline: 2.2174x; 1.5152x over previous
//
#include <hip/hip_runtime.h>
#include <cstddef>

#define EPSF 1e-12f
#define NCB 90
#define NT 30
#define ODIM 256
#define DDIM 8192

typedef unsigned short u16;
typedef __attribute__((ext_vector_type(8))) short short8;
typedef __attribute__((ext_vector_type(4))) float float4v;

__device__ inline u16 f2bf(float f) {
  union { float f; unsigned u; } v; v.f = f;
  unsigned r = v.u + 0x7FFFu + ((v.u >> 16) & 1u);
  return (u16)(r >> 16);
}
__device__ inline float bf2f(u16 h) {
  union { unsigned u; float f; } v; v.u = ((unsigned)h) << 16;
  return v.f;
}

// ---------------------------------------------------------------------------
// K1 (MFMA): per (n, cb): 5 sub-chunks of 32 cols.
//   logits L^T[col][k] = X^T(16col x 32c) @ (Wh+Wl)(32c x 16k)   [w split bf16]
//   softmax over k -> a (bf16) -> P[k][c] += a(16k x 32col) @ X(32col x 16c)
// Frag layouts (m89/m120): A/B lane: [m|n = lane&15][k = (lane>>4)*8+j],
// C/D: col = lane&15, row = (lane>>4)*4 + reg.  LDS 63.4 KB, 2 blocks/CU.
// ---------------------------------------------------------------------------
__global__ __launch_bounds__(256, 2) void k1_assign(
    const float* __restrict__ x,       // [8][128][16][900]
    const float* __restrict__ conv_w,  // [64][128]
    const float* __restrict__ conv_b,  // [64]
    float* __restrict__ P,             // [8][90][64][128]
    float* __restrict__ PA)            // [8][90][64]
{
  __shared__ u16 wfh[8192];        // W-high frags: ((kt*4+cb32)*64+lane)*8+j
  __shared__ u16 wfl[8192];        // W-low frags
  __shared__ u16 xtf[4096];        // logits-layout x: ((colt*4+cb32)*64+lane)*8+j
  __shared__ u16 xf[4096];         // P-layout x: (ct*64+lane)*8+j
  __shared__ float As[64 * 33];    // logits -> exp
  __shared__ u16 afr[2048];        // a frags: (kt*64+lane)*8+j
  __shared__ float Mf[32];
  __shared__ float sm4[128];
  __shared__ float pasum[256];

  const int bx = blockIdx.x;
  const int n = bx / NCB, cb = bx - n * NCB;
  const int t = threadIdx.x;
  const int lane = t & 63;
  const int w = t >> 6;            // wave 0..3

  const float* xn = x + (size_t)n * 1843200 + cb * 10;

  // ---- stage W fragments (split hi/lo), once per block ----
#pragma unroll 4
  for (int i = 0; i < 32; ++i) {
    int e = t + 256 * i;
    int k = e >> 7, c = e & 127;
    float wv = conv_w[e];
    u16 h = f2bf(wv);
    float lo = wv - bf2f(h);
    int idx = (((k >> 4) * 4 + (c >> 5)) * 64 + (((c >> 3) & 3) << 4) + (k & 15)) * 8 + (c & 7);
    wfh[idx] = h;
    wfl[idx] = f2bf(lo);
  }

  // logits tile assignment: wave w -> colt = w&1, kt in {w>>1, (w>>1)+2}
  const int colt = w & 1;
  const int kt0 = w >> 1;
  const float bk0 = conv_b[kt0 * 16 + (lane & 15)];
  const float bk1 = conv_b[(kt0 + 2) * 16 + (lane & 15)];

  float4v pacc[8];
#pragma unroll
  for (int i = 0; i < 8; ++i) pacc[i] = (float4v){0.f, 0.f, 0.f, 0.f};
  float pak = 0.f;

  for (int cc = 0; cc < 5; ++cc) {
    __syncthreads();  // protect frag buffers (covers W staging on cc=0 via next barrier)
    // ---- stage X: float2 global reads (pairs never cross 10-runs), write both layouts ----
#pragma unroll
    for (int s = 0; s < 8; ++s) {
      int e2 = t + 256 * s;
      int c = e2 >> 4, p = e2 & 15;
      int cl = 2 * p;
      int g = cc * 32 + cl;
      int h = g / 10, wi = g - 10 * h;
      float2 val = *(const float2*)(xn + (size_t)c * 14400 + h * 900 + wi);
      u16 h0 = f2bf(val.x), h1 = f2bf(val.y);
      // P layout: both cols land in same lane, consecutive j -> one 4B store
      int ip = ((c >> 4) * 64 + ((cl >> 3) << 4) + (c & 15)) * 8 + (cl & 7);
      ushort2 pr; pr.x = h0; pr.y = h1;
      *(ushort2*)&xf[ip] = pr;
      // logits layout: cols differ in lane -> two 2B stores
      int base_t = (((cl >> 4) * 4 + (c >> 5)) * 64 + (((c >> 3) & 3) << 4)) * 8 + (c & 7);
      xtf[base_t + ((cl & 15) << 3)] = h0;
      xtf[base_t + (((cl + 1) & 15) << 3)] = h1;
    }
    __syncthreads();

    // ---- logits MFMA: L^T = X^T @ (Wh + Wl) ----
    {
      float4v d0 = (float4v){0.f, 0.f, 0.f, 0.f};
      float4v d1 = (float4v){0.f, 0.f, 0.f, 0.f};
#pragma unroll
      for (int cb32 = 0; cb32 < 4; ++cb32) {
        short8 xa = *(short8*)&xtf[((colt * 4 + cb32) * 64 + lane) * 8];
        short8 w0h = *(short8*)&wfh[((kt0 * 4 + cb32) * 64 + lane) * 8];
        short8 w0l = *(short8*)&wfl[((kt0 * 4 + cb32) * 64 + lane) * 8];
        short8 w1h = *(short8*)&wfh[(((kt0 + 2) * 4 + cb32) * 64 + lane) * 8];
        short8 w1l = *(short8*)&wfl[(((kt0 + 2) * 4 + cb32) * 64 + lane) * 8];
        d0 = __builtin_amdgcn_mfma_f32_16x16x32_bf16(xa, w0h, d0, 0, 0, 0);
        d0 = __builtin_amdgcn_mfma_f32_16x16x32_bf16(xa, w0l, d0, 0, 0, 0);
        d1 = __builtin_amdgcn_mfma_f32_16x16x32_bf16(xa, w1h, d1, 0, 0, 0);
        d1 = __builtin_amdgcn_mfma_f32_16x16x32_bf16(xa, w1l, d1, 0, 0, 0);
      }
      // D: row (=col of L^T) = (lane>>4)*4+r, col (=k) = lane&15
      int colb = colt * 16 + ((lane >> 4) << 2);
      int kr0 = kt0 * 16 + (lane & 15);
      int kr1 = (kt0 + 2) * 16 + (lane & 15);
#pragma unroll
      for (int r = 0; r < 4; ++r) {
        As[kr0 * 33 + colb + r] = d0[r] + bk0;
        As[kr1 * 33 + colb + r] = d1[r] + bk1;
      }
    }
    __syncthreads();

    // ---- softmax over k per column ----
    if (t < 32) {
      float m = -3.4e38f;
#pragma unroll
      for (int kk = 0; kk < 64; ++kk) m = fmaxf(m, As[kk * 33 + t]);
      Mf[t] = m;
    }
    __syncthreads();
    if (t < 128) {
      int col = t & 31, kg = t >> 5;
      float M = Mf[col], s = 0.f;
#pragma unroll
      for (int ii = 0; ii < 16; ++ii) {
        int a = (kg * 16 + ii) * 33 + col;
        float e = __expf(As[a] - M);
        As[a] = e;
        s += e;
      }
      sm4[kg * 32 + col] = s;
    }
    __syncthreads();

    // ---- build a-fragments (bf16) + PA partial ----
    {
      int k = t & 63, cg = t >> 6;
      union { u16 u[8]; short8 v; } cvt;
      float paks = 0.f;
#pragma unroll
      for (int j = 0; j < 8; ++j) {
        int col = cg * 8 + j;
        float inv = 1.f / (sm4[col] + sm4[32 + col] + sm4[64 + col] + sm4[96 + col]);
        float a = As[k * 33 + col] * inv;
        paks += a;
        cvt.u[j] = f2bf(a);
      }
      pak += paks;
      int dst = ((k >> 4) * 64 + (cg << 4) + (k & 15)) * 8;
      *(short8*)&afr[dst] = cvt.v;
    }
    __syncthreads();

    // ---- P MFMA: wave w owns kt = w; 8 c-tiles ----
    {
      short8 aa = *(short8*)&afr[(w * 64 + lane) * 8];
#pragma unroll
      for (int ct = 0; ct < 8; ++ct) {
        short8 xb = *(short8*)&xf[(ct * 64 + lane) * 8];
        pacc[ct] = __builtin_amdgcn_mfma_f32_16x16x32_bf16(aa, xb, pacc[ct], 0, 0, 0);
      }
    }
  }

  // ---- write P: D layout: row k = w*16+(lane>>4)*4+r, col c = ct*16+(lane&15) ----
  float* Pp = P + (size_t)(n * NCB + cb) * DDIM;
  {
    int krow = w * 16 + ((lane >> 4) << 2);
    int c0 = lane & 15;
#pragma unroll
    for (int ct = 0; ct < 8; ++ct)
#pragma unroll
      for (int r = 0; r < 4; ++r)
        Pp[(krow + r) * 128 + ct * 16 + c0] = pacc[ct][r];
  }
  // ---- PA reduce across the 4 col-groups ----
  pasum[t] = pak;
  __syncthreads();
  if (t < 64)
    PA[(size_t)(n * NCB + cb) * 64 + t] =
        pasum[t] + pasum[64 + t] + pasum[128 + t] + pasum[192 + t];
}

// ---------------------------------------------------------------------------
// K2: window sums (20 chunks), residual, intra-norm; per-eb global-ss -> gss.
// ---------------------------------------------------------------------------
__global__ __launch_bounds__(256) void k2_vlad(
    const float* __restrict__ P, const float* __restrict__ PA,
    const float* __restrict__ centers, float* __restrict__ vlad,
    float* __restrict__ gss)
{
  __shared__ float Ak[16];
  __shared__ float red[4];
  const int b = blockIdx.x;
  const int win = b >> 2, eb = b & 3;
  const int n = win / NT, wt = win - n * NT;
  const int t = threadIdx.x;

  if (t < 64) {
    int kk = t >> 2, ii = t & 3;
    float s = 0.f;
#pragma unroll
    for (int ss = 0; ss < 5; ++ss) {
      int i = ii + 4 * ss;
      int cb = (3 * wt + 80 + i) % 90;
      s += PA[((size_t)n * NCB + cb) * 64 + eb * 16 + kk];
    }
    s += __shfl_xor(s, 1);
    s += __shfl_xor(s, 2);
    if (ii == 0) Ak[kk] = s;
  }
  __syncthreads();

  const int e0 = eb * 2048 + t * 8;
  float v[8];
#pragma unroll
  for (int j = 0; j < 8; ++j) v[j] = 0.f;
#pragma unroll 5
  for (int i = 0; i < 20; ++i) {
    int cb = (3 * wt + 80 + i) % 90;
    const float* Pp = P + ((size_t)n * NCB + cb) * DDIM + e0;
    float4 u0 = *(const float4*)Pp;
    float4 u1 = *(const float4*)(Pp + 4);
    v[0] += u0.x; v[1] += u0.y; v[2] += u0.z; v[3] += u0.w;
    v[4] += u1.x; v[5] += u1.y; v[6] += u1.z; v[7] += u1.w;
  }
  const float A = Ak[t >> 4];
  const float* ce = centers + e0;
  float ss8 = 0.f;
#pragma unroll
  for (int j = 0; j < 8; ++j) {
    float val = v[j] - ce[j] * A;
    v[j] = val;
    ss8 += val * val;
  }
  float ssg = ss8;
  ssg += __shfl_xor(ssg, 1);
  ssg += __shfl_xor(ssg, 2);
  ssg += __shfl_xor(ssg, 4);
  ssg += __shfl_xor(ssg, 8);
  float rn = 1.f / fmaxf(sqrtf(ssg), EPSF);
#pragma unroll
  for (int j = 0; j < 8; ++j) v[j] *= rn;
  float ts = ss8 * rn * rn;
  ts += __shfl_xor(ts, 1);
  ts += __shfl_xor(ts, 2);
  ts += __shfl_xor(ts, 4);
  ts += __shfl_xor(ts, 8);
  ts += __shfl_xor(ts, 16);
  ts += __shfl_xor(ts, 32);
  if ((t & 63) == 0) red[t >> 6] = ts;
  __syncthreads();
  if (t == 0) gss[(size_t)win * 4 + eb] = red[0] + red[1] + red[2] + red[3];

  float* vp = vlad + (size_t)win * DDIM + e0;
  *(float4*)vp = make_float4(v[0], v[1], v[2], v[3]);
  *(float4*)(vp + 4) = make_float4(v[4], v[5], v[6], v[7]);
}

// ---------------------------------------------------------------------------
// K3: part = (g .* vlad)(240x8192) @ mlp_w^T, split-K x16, tile 16r x 128o
// ---------------------------------------------------------------------------
__global__ __launch_bounds__(256) void k3_gemm(
    const float* __restrict__ vlad, const float* __restrict__ gss,
    const float* __restrict__ mlp_w, float* __restrict__ part)  // [16][240][256]
{
  __shared__ float va[16 * 68];
  __shared__ float wbt[64 * 129];
  __shared__ float ga[16];
  const int bx = blockIdx.x;
  const int rt = bx % 15;
  const int hx = bx / 15;
  const int ot = hx & 1, ks = hx >> 1;
  const int t = threadIdx.x;

  if (t < 16) {
    int r = rt * 16 + t;
    float s = gss[r * 4] + gss[r * 4 + 1] + gss[r * 4 + 2] + gss[r * 4 + 3];
    ga[t] = 1.f / fmaxf(sqrtf(s), EPSF);
  }

  const int rr = (t >> 5) << 1;
  const int o0 = t & 31;
  float acc[2][4];
#pragma unroll
  for (int a = 0; a < 2; ++a)
#pragma unroll
    for (int u = 0; u < 4; ++u) acc[a][u] = 0.f;

  const int d0 = ks * 512;
  for (int dc = 0; dc < 512; dc += 64) {
    __syncthreads();
    {
      int r = t >> 4, dq = t & 15;
      float4 u = *(const float4*)(vlad + (size_t)(rt * 16 + r) * DDIM + d0 + dc + 4 * dq);
      float g = ga[r];
      u.x *= g; u.y *= g; u.z *= g; u.w *= g;
      *(float4*)&va[r * 68 + 4 * dq] = u;
    }
#pragma unroll
    for (int s = 0; s < 8; ++s) {
      int f = t + 256 * s;
      int o = f >> 4, dq = f & 15;
      float4 u = *(const float4*)(mlp_w + (size_t)(ot * 128 + o) * DDIM + d0 + dc + 4 * dq);
      wbt[(4 * dq + 0) * 129 + o] = u.x;
      wbt[(4 * dq + 1) * 129 + o] = u.y;
      wbt[(4 * dq + 2) * 129 + o] = u.z;
      wbt[(4 * dq + 3) * 129 + o] = u.w;
    }
    __syncthreads();
#pragma unroll 8
    for (int dd = 0; dd < 64; ++dd) {
      float x0 = va[rr * 68 + dd];
      float x1 = va[(rr + 1) * 68 + dd];
      float y0 = wbt[dd * 129 + o0];
      float y1 = wbt[dd * 129 + o0 + 32];
      float y2 = wbt[dd * 129 + o0 + 64];
      float y3 = wbt[dd * 129 + o0 + 96];
      acc[0][0] += x0 * y0; acc[0][1] += x0 * y1; acc[0][2] += x0 * y2; acc[0][3] += x0 * y3;
      acc[1][0] += x1 * y0; acc[1][1] += x1 * y1; acc[1][2] += x1 * y2; acc[1][3] += x1 * y3;
    }
  }
  float* pp = part + ((size_t)ks * 240 + rt * 16) * ODIM + ot * 128;
#pragma unroll
  for (int a = 0; a < 2; ++a)
#pragma unroll
    for (int u = 0; u < 4; ++u)
      pp[(rr + a) * ODIM + o0 + 32 * u] = acc[a][u];
}

// ---------------------------------------------------------------------------
// K4: sum split-K partials + bias, row-normalize 240 x 256
// ---------------------------------------------------------------------------
__global__ __launch_bounds__(256) void k4_out(
    const float* __restrict__ part, const float* __restrict__ bias,
    float* __restrict__ out)
{
  __shared__ float red[4];
  const int r = blockIdx.x;
  const int o = threadIdx.x;
  float v = bias[o];
#pragma unroll
  for (int s = 0; s < 16; ++s) v += part[((size_t)s * 240 + r) * ODIM + o];
  float ss = v * v;
  ss += __shfl_xor(ss, 32);
  ss += __shfl_xor(ss, 16);
  ss += __shfl_xor(ss, 8);
  ss += __shfl_xor(ss, 4);
  ss += __shfl_xor(ss, 2);
  ss += __shfl_xor(ss, 1);
  if ((o & 63) == 0) red[o >> 6] = ss;
  __syncthreads();
  float total = red[0] + red[1] + red[2] + red[3];
  out[(size_t)r * ODIM + o] = v / fmaxf(sqrtf(total), EPSF);
}

// ---------------------------------------------------------------------------
extern "C" void kernel_launch(void* const* d_in, const int* in_sizes, int n_in,
                              void* d_out, int out_size, void* d_ws, size_t ws_size,
                              hipStream_t stream) {
  const float* x       = (const float*)d_in[0];
  const float* centers = (const float*)d_in[1];
  const float* conv_w  = (const float*)d_in[2];
  const float* conv_b  = (const float*)d_in[3];
  const float* mlp_w   = (const float*)d_in[4];
  const float* mlp_b   = (const float*)d_in[5];
  float* out = (float*)d_out;

  float* ws   = (float*)d_ws;
  float* P    = ws;                       // 8*90*64*128 = 5,898,240 floats
  float* PA   = P + (size_t)5898240;      // 46,080
  float* vlad = PA + (size_t)46080;       // 240*8192 = 1,966,080
  float* gss  = vlad + (size_t)1966080;   // 960
  float* part = ws;                       // [16][240][256] = 983,040 overlays dead P

  k1_assign<<<dim3(8 * NCB), dim3(256), 0, stream>>>(x, conv_w, conv_b, P, PA);
  k2_vlad  <<<dim3(8 * NT * 4), dim3(256), 0, stream>>>(P, PA, centers, vlad, gss);
  k3_gemm  <<<dim3(480), dim3(256), 0, stream>>>(vlad, gss, mlp_w, part);
  k4_out   <<<dim3(240), dim3(256), 0, stream>>>(part, mlp_b, out);
}